// Round 14
// baseline (10368.099 us; speedup 1.0000x reference)
//
#include <hip/hip_runtime.h>
#include <cstdint>

typedef __bf16 bf16_t;
typedef __attribute__((ext_vector_type(8))) __bf16 bf16x8;
typedef __attribute__((ext_vector_type(4))) __bf16 bf16x4;
typedef __attribute__((ext_vector_type(4))) float f32x4;

#define TOKENS 26896
#define LLEN   1681
#define SDIM   41
#define EDIM   768

// ---------------- async global->LDS 16B ----------------
__device__ __forceinline__ void gload_lds16(const bf16_t* g, bf16_t* l) {
  auto gp = reinterpret_cast<const __attribute__((address_space(1))) char*>(
      reinterpret_cast<uintptr_t>(g));
  auto lp = reinterpret_cast<__attribute__((address_space(3))) char*>(
      reinterpret_cast<uintptr_t>(l));
  __builtin_amdgcn_global_load_lds(gp, lp, 16, 0, 0);
}

enum { EPI_T_POS = 0, EPI_BF16 = 1, EPI_ADD_T = 2, EPI_GELU = 3, EPI_F32 = 4 };

// ============================================================================
// gemm4w (R14): R10/R11 family, tile widened to 128x256.
// BK=32, 256 thr, 4 waves of 64x128 (acc[4][8]) -> 32 MFMA/barrier (2x R13).
// Ring-3 LDS 72KB -> 2 blocks/CU (8 waves; cross-block overlap kept).
// Counted vmcnt(6) (6 staging loads/thread/tile; t+1's retired at step end),
// raw s_barrier + sched_barrier(0), XOR-swizzled LDS (measured 0 conflicts),
// NC=3 col-grouped tile order + bijective XCD swizzle.
// Slot layout (bf16 elems): A[128][32] at 0 (4096), B[256][32] at 4096 (8192);
// slot stride 12288.
// ============================================================================
template <int EPI>
__global__ __launch_bounds__(256, 2) void gemm4_kernel(
    const bf16_t* __restrict__ A, const bf16_t* __restrict__ Bt,
    const float* __restrict__ bias, float* __restrict__ fout,
    bf16_t* __restrict__ bout, const float* __restrict__ pos,
    int M, int N, int K, int ntn, int nwg, int mtiles)
{
  __shared__ bf16_t lds[3 * 12288];   // 72 KB
  const int tid = threadIdx.x, wave = tid >> 6, lane = tid & 63;
  const int wr = wave >> 1, wc = wave & 1;   // 2M x 2N waves, 64x128 each

  int id = blockIdx.x;
  {
    const int q = nwg >> 3, r = nwg & 7;
    const int xcd = id & 7, ix = id >> 3;
    id = (xcd < r ? xcd * (q + 1) : r * (q + 1) + (xcd - r) * q) + ix;
  }
  const int gsz = mtiles * 3;
  const int cg  = id / gsz, rem = id % gsz;
  const int row0 = (rem / 3) * 128;
  const int col0 = (cg * 3 + rem % 3) * 256;
  const int NT = K >> 5;

  const int srow = tid >> 2;                                  // 0..63
  const int sswz = ((tid & 3) ^ ((srow >> 1) & 3)) * 8;       // inv-swz src col
  const bf16_t* aptr[2];
  const bf16_t* bptr[4];
  #pragma unroll
  for (int p = 0; p < 2; ++p) {
    int ar = row0 + p * 64 + srow; if (ar > M - 1) ar = M - 1;
    aptr[p] = A + (size_t)ar * K + sswz;
  }
  #pragma unroll
  for (int p = 0; p < 4; ++p) {
    int br = col0 + p * 64 + srow; if (br > N - 1) br = N - 1;
    bptr[p] = Bt + (size_t)br * K + sswz;
  }
  bf16_t* sdst = lds + tid * 8;

  #define STAGE(BUF, KT) do {                                      \
    const int koff_ = (KT) << 5;                                   \
    gload_lds16(aptr[0] + koff_, sdst + (BUF)*12288);              \
    gload_lds16(aptr[1] + koff_, sdst + (BUF)*12288 + 2048);       \
    gload_lds16(bptr[0] + koff_, sdst + (BUF)*12288 + 4096);       \
    gload_lds16(bptr[1] + koff_, sdst + (BUF)*12288 + 6144);       \
    gload_lds16(bptr[2] + koff_, sdst + (BUF)*12288 + 8192);       \
    gload_lds16(bptr[3] + koff_, sdst + (BUF)*12288 + 10240);      \
  } while (0)

  const int l15 = lane & 15, l4 = lane >> 4;
  const int fswz = (l4 ^ ((l15 >> 1) & 3)) << 3;
  const bf16_t* lA = lds + (wr * 64 + l15) * 32 + fswz;
  const bf16_t* lB = lds + 4096 + (wc * 128 + l15) * 32 + fswz;

  f32x4 acc[4][8] = {};

  #define COMPUTE(BUF) do {                                        \
    bf16x8 fa[4], fb[8];                                           \
    _Pragma("unroll")                                              \
    for (int m_ = 0; m_ < 4; ++m_) fa[m_] = *(const bf16x8*)(lA + (BUF)*12288 + m_*512); \
    _Pragma("unroll")                                              \
    for (int n_ = 0; n_ < 8; ++n_) fb[n_] = *(const bf16x8*)(lB + (BUF)*12288 + n_*512); \
    _Pragma("unroll")                                              \
    for (int m_ = 0; m_ < 4; ++m_)                                 \
      _Pragma("unroll")                                            \
      for (int n_ = 0; n_ < 8; ++n_)                               \
        acc[m_][n_] = __builtin_amdgcn_mfma_f32_16x16x32_bf16(fa[m_], fb[n_], acc[m_][n_], 0, 0, 0); \
  } while (0)

  #define STEP(SC, SN, T) do {                                     \
    if ((T) + 2 < NT) STAGE(SN, (T) + 2);                          \
    COMPUTE(SC);                                                   \
    if ((T) + 2 < NT)      asm volatile("s_waitcnt vmcnt(6)" ::: "memory"); \
    else if ((T) + 1 < NT) asm volatile("s_waitcnt vmcnt(0)" ::: "memory"); \
    __builtin_amdgcn_s_barrier();                                  \
    __builtin_amdgcn_sched_barrier(0);                             \
  } while (0)

  STAGE(0, 0);
  if (NT > 1) {
    STAGE(1, 1);
    asm volatile("s_waitcnt vmcnt(6)" ::: "memory");
  } else {
    asm volatile("s_waitcnt vmcnt(0)" ::: "memory");
  }
  __builtin_amdgcn_s_barrier();
  __builtin_amdgcn_sched_barrier(0);

  for (int kt = 0; kt < NT; kt += 3) {
    STEP(0, 2, kt);
    if (kt + 1 < NT) STEP(1, 0, kt + 1);
    if (kt + 2 < NT) STEP(2, 1, kt + 2);
  }
  #undef STEP
  #undef STAGE
  #undef COMPUTE

  const int rgrp = lane >> 4;
  #pragma unroll
  for (int m = 0; m < 4; ++m) {
    #pragma unroll
    for (int n = 0; n < 8; ++n) {
      const int col = col0 + wc * 128 + n * 16 + l15;
      if (col >= N) continue;
      const int rbase = row0 + wr * 64 + m * 16 + rgrp * 4;
      float bv = 0.f;
      if constexpr (EPI != EPI_F32) bv = bias[col];
      #pragma unroll
      for (int r = 0; r < 4; ++r) {
        const int rr = rbase + r;
        if (rr >= M) continue;
        const float v = acc[m][n][r] + bv;
        const size_t o = (size_t)rr * N + col;
        if constexpr (EPI == EPI_T_POS) {
          const int l = rr % LLEN;
          bout[o] = (bf16_t)(v + pos[(size_t)l * N + col]);
        } else if constexpr (EPI == EPI_BF16) {
          bout[o] = (bf16_t)v;
        } else if constexpr (EPI == EPI_ADD_T) {
          bout[o] = (bf16_t)((float)bout[o] + v);
        } else if constexpr (EPI == EPI_GELU) {
          const float u = v + 0.044715f * v * v * v;
          const float gg = v / (1.f + __expf(-1.5957691216f * u));
          bout[o] = (bf16_t)gg;
        } else {
          fout[o] = v;
        }
      }
    }
  }
}

// ---------------- head GEMM (N=100), simple 128x128 ----------------
__global__ __launch_bounds__(256) void gemm128_f32(
    const bf16_t* __restrict__ A, const bf16_t* __restrict__ Bt,
    float* __restrict__ fout, int M, int N, int K)
{
  __shared__ bf16_t As[128 * 32];
  __shared__ bf16_t Bs[128 * 32];
  const int tid = threadIdx.x, wave = tid >> 6, lane = tid & 63;
  const int row0 = blockIdx.x * 128, col0 = blockIdx.y * 128;
  const int wr = wave >> 1, wc = wave & 1;
  f32x4 acc[4][4] = {};
  const int srow = lane >> 2, skoff = (lane & 3) * 8;
  const int nsteps = K >> 5;
  for (int kt = 0; kt < nsteps; ++kt) {
    const int k0 = kt << 5;
    #pragma unroll
    for (int i = 0; i < 2; ++i) {
      const int r = (i * 4 + wave) * 16 + srow;
      int arow = row0 + r; if (arow > M - 1) arow = M - 1;
      int brow = col0 + r; if (brow > N - 1) brow = N - 1;
      gload_lds16(A  + (size_t)arow * K + k0 + skoff, &As[r * 32 + skoff]);
      gload_lds16(Bt + (size_t)brow * K + k0 + skoff, &Bs[r * 32 + skoff]);
    }
    asm volatile("s_waitcnt vmcnt(0)" ::: "memory");
    __syncthreads();
    const int lrow = lane & 15, lk = (lane >> 4) * 8;
    bf16x8 af[4], bfr[4];
    #pragma unroll
    for (int mi = 0; mi < 4; ++mi)
      af[mi] = *(const bf16x8*)&As[(wr * 64 + mi * 16 + lrow) * 32 + lk];
    #pragma unroll
    for (int ni = 0; ni < 4; ++ni)
      bfr[ni] = *(const bf16x8*)&Bs[(wc * 64 + ni * 16 + lrow) * 32 + lk];
    #pragma unroll
    for (int mi = 0; mi < 4; ++mi)
      #pragma unroll
      for (int ni = 0; ni < 4; ++ni)
        acc[mi][ni] = __builtin_amdgcn_mfma_f32_16x16x32_bf16(af[mi], bfr[ni], acc[mi][ni], 0, 0, 0);
    __syncthreads();
  }
  const int lcol = lane & 15, rgrp = lane >> 4;
  #pragma unroll
  for (int mi = 0; mi < 4; ++mi)
    #pragma unroll
    for (int ni = 0; ni < 4; ++ni) {
      const int col = col0 + wc * 64 + ni * 16 + lcol;
      if (col >= N) continue;
      const int rbase = row0 + wr * 64 + mi * 16 + rgrp * 4;
      #pragma unroll
      for (int r = 0; r < 4; ++r) {
        const int rr = rbase + r;
        if (rr >= M) continue;
        fout[(size_t)rr * N + col] = acc[mi][ni][r];
      }
    }
}

// ---------------- LayerNorm over bf16 t: one wave per token ----------------
__global__ __launch_bounds__(256) void ln_kernel(
    const bf16_t* __restrict__ t, const float* __restrict__ w,
    const float* __restrict__ b, bf16_t* __restrict__ y)
{
  const int token = blockIdx.x * 4 + (threadIdx.x >> 6);
  const int lane  = threadIdx.x & 63;
  const bf16_t* xp = t + (size_t)token * EDIM;
  const bf16x8 a8 = *(const bf16x8*)(xp + lane * 8);
  const bf16x4 a4 = *(const bf16x4*)(xp + 512 + lane * 4);
  float va[12];
  #pragma unroll
  for (int j = 0; j < 8; ++j) va[j] = (float)a8[j];
  #pragma unroll
  for (int j = 0; j < 4; ++j) va[8 + j] = (float)a4[j];
  float s = 0.f;
  #pragma unroll
  for (int j = 0; j < 12; ++j) s += va[j];
  #pragma unroll
  for (int off = 32; off; off >>= 1) s += __shfl_xor(s, off);
  const float mu = s * (1.f / 768.f);
  float q = 0.f;
  #pragma unroll
  for (int j = 0; j < 12; ++j) { const float d = va[j] - mu; q += d * d; }
  #pragma unroll
  for (int off = 32; off; off >>= 1) q += __shfl_xor(q, off);
  const float rs = rsqrtf(q * (1.f / 768.f) + 1e-6f);

  bf16_t* yp = y + (size_t)token * EDIM;
  {
    const int e0 = lane * 8;
    const float4 w0 = ((const float4*)(w + e0))[0];
    const float4 w1 = ((const float4*)(w + e0))[1];
    const float4 b0 = ((const float4*)(b + e0))[0];
    const float4 b1 = ((const float4*)(b + e0))[1];
    bf16x8 o;
    o[0] = (bf16_t)((va[0] - mu) * rs * w0.x + b0.x);
    o[1] = (bf16_t)((va[1] - mu) * rs * w0.y + b0.y);
    o[2] = (bf16_t)((va[2] - mu) * rs * w0.z + b0.z);
    o[3] = (bf16_t)((va[3] - mu) * rs * w0.w + b0.w);
    o[4] = (bf16_t)((va[4] - mu) * rs * w1.x + b1.x);
    o[5] = (bf16_t)((va[5] - mu) * rs * w1.y + b1.y);
    o[6] = (bf16_t)((va[6] - mu) * rs * w1.z + b1.z);
    o[7] = (bf16_t)((va[7] - mu) * rs * w1.w + b1.w);
    *(bf16x8*)(yp + e0) = o;
  }
  {
    const int e0 = 512 + lane * 4;
    const float4 w0 = *(const float4*)(w + e0);
    const float4 b0 = *(const float4*)(b + e0);
    bf16x4 o;
    o[0] = (bf16_t)((va[8]  - mu) * rs * w0.x + b0.x);
    o[1] = (bf16_t)((va[9]  - mu) * rs * w0.y + b0.y);
    o[2] = (bf16_t)((va[10] - mu) * rs * w0.z + b0.z);
    o[3] = (bf16_t)((va[11] - mu) * rs * w0.w + b0.w);
    *(bf16x4*)(yp + e0) = o;
  }
}

// ---------------- row-wise attention (R13-proven float4 version) -----------
__global__ __launch_bounds__(256) void attn_kernel(
    const bf16_t* __restrict__ qkv, bf16_t* __restrict__ o)
{
  const int blk = blockIdx.x;
  const int h  = blk % 12;
  const int bs = blk / 12;
  const int s1 = bs % SDIM;
  const int b  = bs / SDIM;
  __shared__ float Qs[SDIM][68], Ks[SDIM][68], Vs[SDIM][68], Ps[SDIM][44];
  const int tid = threadIdx.x;
  const size_t base = ((size_t)b * LLEN + (size_t)s1 * SDIM);

  for (int idx = tid; idx < SDIM * 8; idx += 256) {
    const int m = idx >> 3, c = idx & 7;
    const bf16_t* p = qkv + (base + m) * 2304 + h * 64 + c * 8;
    const bf16x8 qv = *(const bf16x8*)(p);
    const bf16x8 kv = *(const bf16x8*)(p + 768);
    const bf16x8 vv = *(const bf16x8*)(p + 1536);
    float4 f0, f1;
    f0.x = (float)qv[0]; f0.y = (float)qv[1]; f0.z = (float)qv[2]; f0.w = (float)qv[3];
    f1.x = (float)qv[4]; f1.y = (float)qv[5]; f1.z = (float)qv[6]; f1.w = (float)qv[7];
    *(float4*)&Qs[m][c * 8] = f0; *(float4*)&Qs[m][c * 8 + 4] = f1;
    f0.x = (float)kv[0]; f0.y = (float)kv[1]; f0.z = (float)kv[2]; f0.w = (float)kv[3];
    f1.x = (float)kv[4]; f1.y = (float)kv[5]; f1.z = (float)kv[6]; f1.w = (float)kv[7];
    *(float4*)&Ks[m][c * 8] = f0; *(float4*)&Ks[m][c * 8 + 4] = f1;
    f0.x = (float)vv[0]; f0.y = (float)vv[1]; f0.z = (float)vv[2]; f0.w = (float)vv[3];
    f1.x = (float)vv[4]; f1.y = (float)vv[5]; f1.z = (float)vv[6]; f1.w = (float)vv[7];
    *(float4*)&Vs[m][c * 8] = f0; *(float4*)&Vs[m][c * 8 + 4] = f1;
  }
  __syncthreads();

  for (int idx = tid; idx < SDIM * SDIM; idx += 256) {
    const int n = idx / SDIM, m = idx % SDIM;
    const float4* qn = (const float4*)&Qs[n][0];
    const float4* km = (const float4*)&Ks[m][0];
    float sx = 0.f, sy = 0.f, sz = 0.f, sw = 0.f;
    #pragma unroll
    for (int d4 = 0; d4 < 16; ++d4) {
      const float4 q = qn[d4], k = km[d4];
      sx += q.x * k.x; sy += q.y * k.y; sz += q.z * k.z; sw += q.w * k.w;
    }
    Ps[n][m] = (sx + sy + sz + sw) * 0.125f;
  }
  __syncthreads();

  {
    const int row = tid >> 2, sub = tid & 3;
    if (row < SDIM) {
      float mx = -1e30f;
      for (int m = sub; m < SDIM; m += 4) mx = fmaxf(mx, Ps[row][m]);
      mx = fmaxf(mx, __shfl_xor(mx, 1));
      mx = fmaxf(mx, __shfl_xor(mx, 2));
      float sum = 0.f;
      for (int m = sub; m < SDIM; m += 4) {
        const float e = __expf(Ps[row][m] - mx);
        Ps[row][m] = e;
        sum += e;
      }
      sum += __shfl_xor(sum, 1);
      sum += __shfl_xor(sum, 2);
      const float inv = 1.f / sum;
      for (int m = sub; m < SDIM; m += 4) Ps[row][m] *= inv;
    }
  }
  __syncthreads();

  for (int idx = tid; idx < SDIM * 16; idx += 256) {
    const int n = idx >> 4, dq = idx & 15;
    float ax = 0.f, ay = 0.f, az = 0.f, aw = 0.f;
    #pragma unroll
    for (int m = 0; m < SDIM; ++m) {
      const float pm = Ps[n][m];
      const float4 v = *(const float4*)&Vs[m][dq * 4];
      ax += pm * v.x; ay += pm * v.y; az += pm * v.z; aw += pm * v.w;
    }
    bf16x4 ov;
    ov[0] = (bf16_t)ax; ov[1] = (bf16_t)ay; ov[2] = (bf16_t)az; ov[3] = (bf16_t)aw;
    *(bf16x4*)(o + (base + n) * EDIM + h * 64 + dq * 4) = ov;
  }
}

// ---------------- transpose fp32(KxN) -> bf16(NxK) ----------------
__global__ __launch_bounds__(256) void transpose_kernel(
    const float* __restrict__ in, bf16_t* __restrict__ out, int K, int N)
{
  __shared__ float tile[32][33];
  const int k0 = blockIdx.x * 32, n0 = blockIdx.y * 32;
  const int tx = threadIdx.x & 31, ty = threadIdx.x >> 5;
  #pragma unroll
  for (int i = 0; i < 32; i += 8) {
    const int k = k0 + ty + i, n = n0 + tx;
    if (k < K && n < N) tile[ty + i][tx] = in[(size_t)k * N + n];
  }
  __syncthreads();
  #pragma unroll
  for (int i = 0; i < 32; i += 8) {
    const int n = n0 + ty + i, k = k0 + tx;
    if (n < N && k < K) out[(size_t)n * K + k] = (bf16_t)tile[tx][ty + i];
  }
}

// ---------------- im2col for conv1 chunk (pad K 1200->1216) ----------------
__global__ __launch_bounds__(256) void im2col_kernel(
    const float* __restrict__ x, bf16_t* __restrict__ col, int tok0, int ntok)
{
  const size_t idx = (size_t)blockIdx.x * 256 + threadIdx.x;
  if (idx >= (size_t)ntok * 1216) return;
  const int kk = (int)(idx % 1216);
  const size_t tok = tok0 + idx / 1216;
  const int b = (int)(tok / LLEN), l = (int)(tok % LLEN);
  const int s1 = l / SDIM, s2 = l % SDIM;
  float v = 0.f;
  if (kk < 1200) {
    const int cin = kk / 100, r = kk % 100, ky = r / 10, kx = r % 10;
    const int iy = s1 - 5 + ky, ix = s2 - 5 + kx;
    if (iy >= 0 && iy < 40 && ix >= 0 && ix < 40)
      v = x[((size_t)(b * 12 + cin) * 40 + iy) * 40 + ix];
  }
  col[idx] = (bf16_t)v;
}

__global__ __launch_bounds__(256) void convw_kernel(
    const float* __restrict__ w, bf16_t* __restrict__ out)
{
  const int idx = blockIdx.x * 256 + threadIdx.x;
  const int kk = idx % 1216, e = idx / 1216;
  const float v = (kk < 1200) ? w[(size_t)e * 1200 + kk] : 0.f;
  out[idx] = (bf16_t)v;
}

__global__ __launch_bounds__(256) void tconvw_kernel(
    const float* __restrict__ w, bf16_t* __restrict__ out)
{
  const int idx = blockIdx.x * 256 + threadIdx.x;  // 100*768
  const int e = idx % 768, tap = idx / 768;
  const int ky = tap / 10, kx = tap % 10;
  out[idx] = (bf16_t)w[(size_t)e * 100 + (9 - ky) * 10 + (9 - kx)];
}

// ---------------- final gather ----------------
__global__ __launch_bounds__(256) void outconv_kernel(
    const float* __restrict__ g, const float* __restrict__ tb,
    float* __restrict__ out)
{
  const int idx = blockIdx.x * 256 + threadIdx.x;
  if (idx >= 16 * 40 * 40) return;
  const int x = idx % 40, y = (idx / 40) % 40, b = idx / 1600;
  float s = tb[0];
  #pragma unroll
  for (int ky = 0; ky < 10; ++ky) {
    const int ty_ = y - 4 + ky;
    if (ty_ < 0 || ty_ >= SDIM) continue;
    #pragma unroll
    for (int kx = 0; kx < 10; ++kx) {
      const int tx_ = x - 4 + kx;
      if (tx_ < 0 || tx_ >= SDIM) continue;
      s += g[((size_t)b * LLEN + ty_ * SDIM + tx_) * 100 + ky * 10 + kx];
    }
  }
  out[idx] = s;
}

// ============================================================================
extern "C" void kernel_launch(void* const* d_in, const int* in_sizes, int n_in,
                              void* d_out, int out_size, void* d_ws, size_t ws_size,
                              hipStream_t stream)
{
  const float* x       = (const float*)d_in[0];
  const float* conv_w  = (const float*)d_in[1];
  const float* conv_b  = (const float*)d_in[2];
  const float* pos     = (const float*)d_in[3];
  const float* ln1_w   = (const float*)d_in[4];
  const float* ln1_b   = (const float*)d_in[5];
  const float* qkv_w   = (const float*)d_in[6];
  const float* qkv_b   = (const float*)d_in[7];
  const float* proj_w  = (const float*)d_in[8];
  const float* proj_b  = (const float*)d_in[9];
  const float* ln2_w   = (const float*)d_in[10];
  const float* ln2_b   = (const float*)d_in[11];
  const float* fc1_w   = (const float*)d_in[12];
  const float* fc1_b   = (const float*)d_in[13];
  const float* fc2_w   = (const float*)d_in[14];
  const float* fc2_b   = (const float*)d_in[15];
  const float* lnf_w   = (const float*)d_in[16];
  const float* lnf_b   = (const float*)d_in[17];
  const float* tconv_w = (const float*)d_in[18];
  const float* tconv_b = (const float*)d_in[19];
  float* out = (float*)d_out;

  // ---- workspace tiers (bf16 t): nch=1 262MB / nch=2 180MB / nch=4 138MB
  const int nch = (ws_size >= 262200000UL) ? 1
                : (ws_size >= 179500000UL) ? 2 : 4;
  const int cht = TOKENS / nch;

  char* p = (char*)d_ws;
  auto alloc = [&](size_t bytes) {
    char* r = p;
    p += (bytes + 255) & ~(size_t)255;
    return r;
  };
  bf16_t* wbuf = (bf16_t*)alloc((size_t)768 * 9216 * 2);
  bf16_t* t    = (bf16_t*)alloc((size_t)TOKENS * EDIM * 2);
  bf16_t* ybuf = (bf16_t*)alloc((size_t)TOKENS * EDIM * 2);
  bf16_t* hbuf = (bf16_t*)alloc((size_t)cht * 3072 * 2);

  bf16_t* Wq = wbuf;
  bf16_t* Wp = Wq + (size_t)2304 * 768;
  bf16_t* W1 = Wp + (size_t)768 * 768;
  bf16_t* W2 = W1 + (size_t)3072 * 768;

  auto g4 = [&](int epi, const bf16_t* A, const bf16_t* Bt,
                const float* bias, bf16_t* bo, const float* pe,
                int M, int N, int K) {
    const int mtiles = (M + 127) / 128;
    const int ntn = N / 256;
    const int nwg = mtiles * ntn;
    switch (epi) {
      case EPI_T_POS: gemm4_kernel<EPI_T_POS><<<nwg, 256, 0, stream>>>(A, Bt, bias, nullptr, bo, pe, M, N, K, ntn, nwg, mtiles); break;
      case EPI_BF16:  gemm4_kernel<EPI_BF16 ><<<nwg, 256, 0, stream>>>(A, Bt, bias, nullptr, bo, pe, M, N, K, ntn, nwg, mtiles); break;
      case EPI_ADD_T: gemm4_kernel<EPI_ADD_T><<<nwg, 256, 0, stream>>>(A, Bt, bias, nullptr, bo, pe, M, N, K, ntn, nwg, mtiles); break;
      default:        gemm4_kernel<EPI_GELU ><<<nwg, 256, 0, stream>>>(A, Bt, bias, nullptr, bo, pe, M, N, K, ntn, nwg, mtiles); break;
    }
  };

  // ---- conv1 as chunked im2col GEMM -> t (+bias +pos_embed), bf16 ----
  convw_kernel<<<(768 * 1216) / 256, 256, 0, stream>>>(conv_w, wbuf);
  for (int c = 0; c < nch; ++c) {
    const int tok0 = c * cht;
    im2col_kernel<<<(unsigned)(((size_t)cht * 1216 + 255) / 256), 256, 0, stream>>>(x, hbuf, tok0, cht);
    g4(EPI_T_POS, hbuf, wbuf, conv_b, t + (size_t)tok0 * EDIM, pos, cht, EDIM, 1216);
  }

  // ---- transformer layers ----
  for (int i = 0; i < 12; ++i) {
    transpose_kernel<<<dim3(24, 72), 256, 0, stream>>>(qkv_w + (size_t)i * 768 * 2304, Wq, 768, 2304);
    transpose_kernel<<<dim3(24, 24), 256, 0, stream>>>(proj_w + (size_t)i * 768 * 768, Wp, 768, 768);
    transpose_kernel<<<dim3(24, 96), 256, 0, stream>>>(fc1_w + (size_t)i * 768 * 3072, W1, 768, 3072);
    transpose_kernel<<<dim3(96, 24), 256, 0, stream>>>(fc2_w + (size_t)i * 3072 * 768, W2, 3072, 768);

    ln_kernel<<<TOKENS / 4, 256, 0, stream>>>(t, ln1_w + i * EDIM, ln1_b + i * EDIM, ybuf);
    for (int c = 0; c < nch; ++c) {
      const size_t ro = (size_t)c * cht;
      g4(EPI_BF16, ybuf + ro * EDIM, Wq, qkv_b + i * 2304, hbuf, nullptr, cht, 2304, 768);
      attn_kernel<<<(16 / nch) * SDIM * 12, 256, 0, stream>>>(hbuf, ybuf + ro * EDIM);
    }
    g4(EPI_ADD_T, ybuf, Wp, proj_b + i * EDIM, t, nullptr, TOKENS, EDIM, 768);

    ln_kernel<<<TOKENS / 4, 256, 0, stream>>>(t, ln2_w + i * EDIM, ln2_b + i * EDIM, ybuf);
    for (int c = 0; c < nch; ++c) {
      const size_t ro = (size_t)c * cht;
      g4(EPI_GELU, ybuf + ro * EDIM, W1, fc1_b + i * 3072, hbuf, nullptr, cht, 3072, 768);
      g4(EPI_ADD_T, hbuf, W2, fc2_b + i * EDIM, t + ro * EDIM, nullptr, cht, EDIM, 3072);
    }
  }

  // ---- final LN + tconv head ----
  ln_kernel<<<TOKENS / 4, 256, 0, stream>>>(t, lnf_w, lnf_b, ybuf);
  tconvw_kernel<<<(100 * 768) / 256, 256, 0, stream>>>(tconv_w, wbuf);
  gemm128_f32<<<dim3((TOKENS + 127) / 128, 1), 256, 0, stream>>>(ybuf, wbuf, (float*)hbuf, TOKENS, 100, 768);
  outconv_kernel<<<100, 256, 0, stream>>>((const float*)hbuf, tconv_b, out);
}

// Round 15
// 8990.424 us; speedup vs baseline: 1.1532x; 1.1532x over previous
//
#include <hip/hip_runtime.h>
#include <cstdint>

typedef __bf16 bf16_t;
typedef __attribute__((ext_vector_type(8))) __bf16 bf16x8;
typedef __attribute__((ext_vector_type(4))) __bf16 bf16x4;
typedef __attribute__((ext_vector_type(4))) float f32x4;

#define TOKENS 26896
#define LLEN   1681
#define SDIM   41
#define EDIM   768

// ---------------- async global->LDS 16B ----------------
__device__ __forceinline__ void gload_lds16(const bf16_t* g, bf16_t* l) {
  auto gp = reinterpret_cast<const __attribute__((address_space(1))) char*>(
      reinterpret_cast<uintptr_t>(g));
  auto lp = reinterpret_cast<__attribute__((address_space(3))) char*>(
      reinterpret_cast<uintptr_t>(l));
  __builtin_amdgcn_global_load_lds(gp, lp, 16, 0, 0);
}

enum { EPI_T_POS = 0, EPI_BF16 = 1, EPI_ADD_T = 2, EPI_GELU = 3, EPI_F32 = 4 };

// ============================================================================
// gemm4r (R10/R11/R13-proven optimum of this family): 128x128 tile, BK=32,
// 256 thr, ring-3 LDS 48KB -> 3 blocks/CU, counted vmcnt(4), raw s_barrier +
// sched_barrier(0), XOR-swizzled LDS (0 conflicts measured), NC=6
// col-grouped tile order + bijective XCD swizzle (96MB near-ideal FETCH).
// Neighbor configs falsified: 1blk/CU 2ph (R7), runtime-ring (R6), 8-phase
// port (R12), 128x256 2blk (R14) -- all regress.
// ============================================================================
template <int EPI>
__global__ __launch_bounds__(256, 3) void gemm4_kernel(
    const bf16_t* __restrict__ A, const bf16_t* __restrict__ Bt,
    const float* __restrict__ bias, float* __restrict__ fout,
    bf16_t* __restrict__ bout, const float* __restrict__ pos,
    int M, int N, int K, int ntn, int nwg, int mtiles)
{
  __shared__ bf16_t lds[3 * 8192];
  const int tid = threadIdx.x, wave = tid >> 6, lane = tid & 63;
  const int wr = wave >> 1, wc = wave & 1;

  int id = blockIdx.x;
  {
    const int q = nwg >> 3, r = nwg & 7;
    const int xcd = id & 7, ix = id >> 3;
    id = (xcd < r ? xcd * (q + 1) : r * (q + 1) + (xcd - r) * q) + ix;
  }
  const int gsz = mtiles * 6;
  const int cg  = id / gsz, rem = id % gsz;
  const int row0 = (rem / 6) * 128;
  const int col0 = (cg * 6 + rem % 6) * 128;
  const int NT = K >> 5;

  const int srow = tid >> 2;
  const int sswz = ((tid & 3) ^ ((srow >> 1) & 3)) * 8;
  const bf16_t* aptr[2];
  const bf16_t* bptr[2];
  #pragma unroll
  for (int p = 0; p < 2; ++p) {
    int ar = row0 + p * 64 + srow; if (ar > M - 1) ar = M - 1;
    int br = col0 + p * 64 + srow; if (br > N - 1) br = N - 1;
    aptr[p] = A  + (size_t)ar * K + sswz;
    bptr[p] = Bt + (size_t)br * K + sswz;
  }
  bf16_t* sdst = lds + tid * 8;

  #define STAGE(BUF, KT) do {                                   \
    const int koff_ = (KT) << 5;                                \
    gload_lds16(aptr[0] + koff_, sdst + (BUF)*8192);            \
    gload_lds16(aptr[1] + koff_, sdst + (BUF)*8192 + 2048);     \
    gload_lds16(bptr[0] + koff_, sdst + (BUF)*8192 + 4096);     \
    gload_lds16(bptr[1] + koff_, sdst + (BUF)*8192 + 6144);     \
  } while (0)

  const int l15 = lane & 15, l4 = lane >> 4;
  const int fswz = (l4 ^ ((l15 >> 1) & 3)) << 3;
  const bf16_t* lA = lds + (wr * 64 + l15) * 32 + fswz;
  const bf16_t* lB = lds + 4096 + (wc * 64 + l15) * 32 + fswz;

  f32x4 acc[4][4] = {};

  #define COMPUTE(BUF) do {                                     \
    bf16x8 fa[4], fb[4];                                        \
    _Pragma("unroll")                                           \
    for (int m_ = 0; m_ < 4; ++m_) fa[m_] = *(const bf16x8*)(lA + (BUF)*8192 + m_*512); \
    _Pragma("unroll")                                           \
    for (int n_ = 0; n_ < 4; ++n_) fb[n_] = *(const bf16x8*)(lB + (BUF)*8192 + n_*512); \
    _Pragma("unroll")                                           \
    for (int m_ = 0; m_ < 4; ++m_)                              \
      _Pragma("unroll")                                         \
      for (int n_ = 0; n_ < 4; ++n_)                            \
        acc[m_][n_] = __builtin_amdgcn_mfma_f32_16x16x32_bf16(fa[m_], fb[n_], acc[m_][n_], 0, 0, 0); \
  } while (0)

  #define STEP(SC, SN, T) do {                                  \
    if ((T) + 2 < NT) STAGE(SN, (T) + 2);                       \
    COMPUTE(SC);                                                \
    if ((T) + 2 < NT)      asm volatile("s_waitcnt vmcnt(4)" ::: "memory"); \
    else if ((T) + 1 < NT) asm volatile("s_waitcnt vmcnt(0)" ::: "memory"); \
    __builtin_amdgcn_s_barrier();                               \
    __builtin_amdgcn_sched_barrier(0);                          \
  } while (0)

  STAGE(0, 0);
  if (NT > 1) {
    STAGE(1, 1);
    asm volatile("s_waitcnt vmcnt(4)" ::: "memory");
  } else {
    asm volatile("s_waitcnt vmcnt(0)" ::: "memory");
  }
  __builtin_amdgcn_s_barrier();
  __builtin_amdgcn_sched_barrier(0);

  for (int kt = 0; kt < NT; kt += 3) {
    STEP(0, 2, kt);
    if (kt + 1 < NT) STEP(1, 0, kt + 1);
    if (kt + 2 < NT) STEP(2, 1, kt + 2);
  }
  #undef STEP
  #undef STAGE
  #undef COMPUTE

  const int rgrp = lane >> 4;
  #pragma unroll
  for (int m = 0; m < 4; ++m) {
    #pragma unroll
    for (int n = 0; n < 4; ++n) {
      const int col = col0 + wc * 64 + n * 16 + l15;
      if (col >= N) continue;
      const int rbase = row0 + wr * 64 + m * 16 + rgrp * 4;
      float bv = 0.f;
      if constexpr (EPI != EPI_F32) bv = bias[col];
      #pragma unroll
      for (int r = 0; r < 4; ++r) {
        const int rr = rbase + r;
        if (rr >= M) continue;
        const float v = acc[m][n][r] + bv;
        const size_t o = (size_t)rr * N + col;
        if constexpr (EPI == EPI_T_POS) {
          const int l = rr % LLEN;
          bout[o] = (bf16_t)(v + pos[(size_t)l * N + col]);
        } else if constexpr (EPI == EPI_BF16) {
          bout[o] = (bf16_t)v;
        } else if constexpr (EPI == EPI_ADD_T) {
          bout[o] = (bf16_t)((float)bout[o] + v);
        } else if constexpr (EPI == EPI_GELU) {
          const float u = v + 0.044715f * v * v * v;
          const float gg = v / (1.f + __expf(-1.5957691216f * u));
          bout[o] = (bf16_t)gg;
        } else {
          fout[o] = v;
        }
      }
    }
  }
}

// ---------------- head GEMM (N=100), simple 128x128 ----------------
__global__ __launch_bounds__(256) void gemm128_f32(
    const bf16_t* __restrict__ A, const bf16_t* __restrict__ Bt,
    float* __restrict__ fout, int M, int N, int K)
{
  __shared__ bf16_t As[128 * 32];
  __shared__ bf16_t Bs[128 * 32];
  const int tid = threadIdx.x, wave = tid >> 6, lane = tid & 63;
  const int row0 = blockIdx.x * 128, col0 = blockIdx.y * 128;
  const int wr = wave >> 1, wc = wave & 1;
  f32x4 acc[4][4] = {};
  const int srow = lane >> 2, skoff = (lane & 3) * 8;
  const int nsteps = K >> 5;
  for (int kt = 0; kt < nsteps; ++kt) {
    const int k0 = kt << 5;
    #pragma unroll
    for (int i = 0; i < 2; ++i) {
      const int r = (i * 4 + wave) * 16 + srow;
      int arow = row0 + r; if (arow > M - 1) arow = M - 1;
      int brow = col0 + r; if (brow > N - 1) brow = N - 1;
      gload_lds16(A  + (size_t)arow * K + k0 + skoff, &As[r * 32 + skoff]);
      gload_lds16(Bt + (size_t)brow * K + k0 + skoff, &Bs[r * 32 + skoff]);
    }
    asm volatile("s_waitcnt vmcnt(0)" ::: "memory");
    __syncthreads();
    const int lrow = lane & 15, lk = (lane >> 4) * 8;
    bf16x8 af[4], bfr[4];
    #pragma unroll
    for (int mi = 0; mi < 4; ++mi)
      af[mi] = *(const bf16x8*)&As[(wr * 64 + mi * 16 + lrow) * 32 + lk];
    #pragma unroll
    for (int ni = 0; ni < 4; ++ni)
      bfr[ni] = *(const bf16x8*)&Bs[(wc * 64 + ni * 16 + lrow) * 32 + lk];
    #pragma unroll
    for (int mi = 0; mi < 4; ++mi)
      #pragma unroll
      for (int ni = 0; ni < 4; ++ni)
        acc[mi][ni] = __builtin_amdgcn_mfma_f32_16x16x32_bf16(af[mi], bfr[ni], acc[mi][ni], 0, 0, 0);
    __syncthreads();
  }
  const int lcol = lane & 15, rgrp = lane >> 4;
  #pragma unroll
  for (int mi = 0; mi < 4; ++mi)
    #pragma unroll
    for (int ni = 0; ni < 4; ++ni) {
      const int col = col0 + wc * 64 + ni * 16 + lcol;
      if (col >= N) continue;
      const int rbase = row0 + wr * 64 + mi * 16 + rgrp * 4;
      #pragma unroll
      for (int r = 0; r < 4; ++r) {
        const int rr = rbase + r;
        if (rr >= M) continue;
        fout[(size_t)rr * N + col] = acc[mi][ni][r];
      }
    }
}

// ---------------- LayerNorm over bf16 t: one wave per token ----------------
__global__ __launch_bounds__(256) void ln_kernel(
    const bf16_t* __restrict__ t, const float* __restrict__ w,
    const float* __restrict__ b, bf16_t* __restrict__ y)
{
  const int token = blockIdx.x * 4 + (threadIdx.x >> 6);
  const int lane  = threadIdx.x & 63;
  const bf16_t* xp = t + (size_t)token * EDIM;
  const bf16x8 a8 = *(const bf16x8*)(xp + lane * 8);
  const bf16x4 a4 = *(const bf16x4*)(xp + 512 + lane * 4);
  float va[12];
  #pragma unroll
  for (int j = 0; j < 8; ++j) va[j] = (float)a8[j];
  #pragma unroll
  for (int j = 0; j < 4; ++j) va[8 + j] = (float)a4[j];
  float s = 0.f;
  #pragma unroll
  for (int j = 0; j < 12; ++j) s += va[j];
  #pragma unroll
  for (int off = 32; off; off >>= 1) s += __shfl_xor(s, off);
  const float mu = s * (1.f / 768.f);
  float q = 0.f;
  #pragma unroll
  for (int j = 0; j < 12; ++j) { const float d = va[j] - mu; q += d * d; }
  #pragma unroll
  for (int off = 32; off; off >>= 1) q += __shfl_xor(q, off);
  const float rs = rsqrtf(q * (1.f / 768.f) + 1e-6f);

  bf16_t* yp = y + (size_t)token * EDIM;
  {
    const int e0 = lane * 8;
    const float4 w0 = ((const float4*)(w + e0))[0];
    const float4 w1 = ((const float4*)(w + e0))[1];
    const float4 b0 = ((const float4*)(b + e0))[0];
    const float4 b1 = ((const float4*)(b + e0))[1];
    bf16x8 o;
    o[0] = (bf16_t)((va[0] - mu) * rs * w0.x + b0.x);
    o[1] = (bf16_t)((va[1] - mu) * rs * w0.y + b0.y);
    o[2] = (bf16_t)((va[2] - mu) * rs * w0.z + b0.z);
    o[3] = (bf16_t)((va[3] - mu) * rs * w0.w + b0.w);
    o[4] = (bf16_t)((va[4] - mu) * rs * w1.x + b1.x);
    o[5] = (bf16_t)((va[5] - mu) * rs * w1.y + b1.y);
    o[6] = (bf16_t)((va[6] - mu) * rs * w1.z + b1.z);
    o[7] = (bf16_t)((va[7] - mu) * rs * w1.w + b1.w);
    *(bf16x8*)(yp + e0) = o;
  }
  {
    const int e0 = 512 + lane * 4;
    const float4 w0 = *(const float4*)(w + e0);
    const float4 b0 = *(const float4*)(b + e0);
    bf16x4 o;
    o[0] = (bf16_t)((va[8]  - mu) * rs * w0.x + b0.x);
    o[1] = (bf16_t)((va[9]  - mu) * rs * w0.y + b0.y);
    o[2] = (bf16_t)((va[10] - mu) * rs * w0.z + b0.z);
    o[3] = (bf16_t)((va[11] - mu) * rs * w0.w + b0.w);
    *(bf16x4*)(yp + e0) = o;
  }
}

// ---------------- row-wise attention (R13-proven float4 version) -----------
__global__ __launch_bounds__(256) void attn_kernel(
    const bf16_t* __restrict__ qkv, bf16_t* __restrict__ o)
{
  const int blk = blockIdx.x;
  const int h  = blk % 12;
  const int bs = blk / 12;
  const int s1 = bs % SDIM;
  const int b  = bs / SDIM;
  __shared__ float Qs[SDIM][68], Ks[SDIM][68], Vs[SDIM][68], Ps[SDIM][44];
  const int tid = threadIdx.x;
  const size_t base = ((size_t)b * LLEN + (size_t)s1 * SDIM);

  for (int idx = tid; idx < SDIM * 8; idx += 256) {
    const int m = idx >> 3, c = idx & 7;
    const bf16_t* p = qkv + (base + m) * 2304 + h * 64 + c * 8;
    const bf16x8 qv = *(const bf16x8*)(p);
    const bf16x8 kv = *(const bf16x8*)(p + 768);
    const bf16x8 vv = *(const bf16x8*)(p + 1536);
    float4 f0, f1;
    f0.x = (float)qv[0]; f0.y = (float)qv[1]; f0.z = (float)qv[2]; f0.w = (float)qv[3];
    f1.x = (float)qv[4]; f1.y = (float)qv[5]; f1.z = (float)qv[6]; f1.w = (float)qv[7];
    *(float4*)&Qs[m][c * 8] = f0; *(float4*)&Qs[m][c * 8 + 4] = f1;
    f0.x = (float)kv[0]; f0.y = (float)kv[1]; f0.z = (float)kv[2]; f0.w = (float)kv[3];
    f1.x = (float)kv[4]; f1.y = (float)kv[5]; f1.z = (float)kv[6]; f1.w = (float)kv[7];
    *(float4*)&Ks[m][c * 8] = f0; *(float4*)&Ks[m][c * 8 + 4] = f1;
    f0.x = (float)vv[0]; f0.y = (float)vv[1]; f0.z = (float)vv[2]; f0.w = (float)vv[3];
    f1.x = (float)vv[4]; f1.y = (float)vv[5]; f1.z = (float)vv[6]; f1.w = (float)vv[7];
    *(float4*)&Vs[m][c * 8] = f0; *(float4*)&Vs[m][c * 8 + 4] = f1;
  }
  __syncthreads();

  for (int idx = tid; idx < SDIM * SDIM; idx += 256) {
    const int n = idx / SDIM, m = idx % SDIM;
    const float4* qn = (const float4*)&Qs[n][0];
    const float4* km = (const float4*)&Ks[m][0];
    float sx = 0.f, sy = 0.f, sz = 0.f, sw = 0.f;
    #pragma unroll
    for (int d4 = 0; d4 < 16; ++d4) {
      const float4 q = qn[d4], k = km[d4];
      sx += q.x * k.x; sy += q.y * k.y; sz += q.z * k.z; sw += q.w * k.w;
    }
    Ps[n][m] = (sx + sy + sz + sw) * 0.125f;
  }
  __syncthreads();

  {
    const int row = tid >> 2, sub = tid & 3;
    if (row < SDIM) {
      float mx = -1e30f;
      for (int m = sub; m < SDIM; m += 4) mx = fmaxf(mx, Ps[row][m]);
      mx = fmaxf(mx, __shfl_xor(mx, 1));
      mx = fmaxf(mx, __shfl_xor(mx, 2));
      float sum = 0.f;
      for (int m = sub; m < SDIM; m += 4) {
        const float e = __expf(Ps[row][m] - mx);
        Ps[row][m] = e;
        sum += e;
      }
      sum += __shfl_xor(sum, 1);
      sum += __shfl_xor(sum, 2);
      const float inv = 1.f / sum;
      for (int m = sub; m < SDIM; m += 4) Ps[row][m] *= inv;
    }
  }
  __syncthreads();

  for (int idx = tid; idx < SDIM * 16; idx += 256) {
    const int n = idx >> 4, dq = idx & 15;
    float ax = 0.f, ay = 0.f, az = 0.f, aw = 0.f;
    #pragma unroll
    for (int m = 0; m < SDIM; ++m) {
      const float pm = Ps[n][m];
      const float4 v = *(const float4*)&Vs[m][dq * 4];
      ax += pm * v.x; ay += pm * v.y; az += pm * v.z; aw += pm * v.w;
    }
    bf16x4 ov;
    ov[0] = (bf16_t)ax; ov[1] = (bf16_t)ay; ov[2] = (bf16_t)az; ov[3] = (bf16_t)aw;
    *(bf16x4*)(o + (base + n) * EDIM + h * 64 + dq * 4) = ov;
  }
}

// ---------------- combined per-layer weight transpose (4 -> 1 launch) ------
// Ranges (32x32 tiles): qkv 768x2304 -> 1728, proj 768x768 -> 576,
// fc1 768x3072 -> 2304, fc2 3072x768 -> 2304. Total 6912 blocks.
__device__ __forceinline__ void tr_tile(
    const float* __restrict__ in, bf16_t* __restrict__ out,
    int K, int N, int tile, int tid)
{
  __shared__ float tls[32][33];
  const int ntn = N >> 5;
  const int k0 = (tile / ntn) * 32, n0 = (tile % ntn) * 32;
  const int tx = tid & 31, ty = tid >> 5;
  #pragma unroll
  for (int i = 0; i < 32; i += 8)
    tls[ty + i][tx] = in[(size_t)(k0 + ty + i) * N + n0 + tx];
  __syncthreads();
  #pragma unroll
  for (int i = 0; i < 32; i += 8)
    out[(size_t)(n0 + ty + i) * K + k0 + tx] = (bf16_t)tls[tx][ty + i];
}

__global__ __launch_bounds__(256) void transpose4_kernel(
    const float* __restrict__ qw, const float* __restrict__ pw,
    const float* __restrict__ f1, const float* __restrict__ f2,
    bf16_t* __restrict__ Wq, bf16_t* __restrict__ Wp,
    bf16_t* __restrict__ W1, bf16_t* __restrict__ W2)
{
  const int b = blockIdx.x, tid = threadIdx.x;
  if (b < 1728)       tr_tile(qw, Wq, 768, 2304, b, tid);
  else if (b < 2304)  tr_tile(pw, Wp, 768, 768, b - 1728, tid);
  else if (b < 4608)  tr_tile(f1, W1, 768, 3072, b - 2304, tid);
  else                tr_tile(f2, W2, 3072, 768, b - 4608, tid);
}

// ---------------- im2col for conv1 chunk (pad K 1200->1216) ----------------
__global__ __launch_bounds__(256) void im2col_kernel(
    const float* __restrict__ x, bf16_t* __restrict__ col, int tok0, int ntok)
{
  const size_t idx = (size_t)blockIdx.x * 256 + threadIdx.x;
  if (idx >= (size_t)ntok * 1216) return;
  const int kk = (int)(idx % 1216);
  const size_t tok = tok0 + idx / 1216;
  const int b = (int)(tok / LLEN), l = (int)(tok % LLEN);
  const int s1 = l / SDIM, s2 = l % SDIM;
  float v = 0.f;
  if (kk < 1200) {
    const int cin = kk / 100, r = kk % 100, ky = r / 10, kx = r % 10;
    const int iy = s1 - 5 + ky, ix = s2 - 5 + kx;
    if (iy >= 0 && iy < 40 && ix >= 0 && ix < 40)
      v = x[((size_t)(b * 12 + cin) * 40 + iy) * 40 + ix];
  }
  col[idx] = (bf16_t)v;
}

__global__ __launch_bounds__(256) void convw_kernel(
    const float* __restrict__ w, bf16_t* __restrict__ out)
{
  const int idx = blockIdx.x * 256 + threadIdx.x;
  const int kk = idx % 1216, e = idx / 1216;
  const float v = (kk < 1200) ? w[(size_t)e * 1200 + kk] : 0.f;
  out[idx] = (bf16_t)v;
}

__global__ __launch_bounds__(256) void tconvw_kernel(
    const float* __restrict__ w, bf16_t* __restrict__ out)
{
  const int idx = blockIdx.x * 256 + threadIdx.x;  // 100*768
  const int e = idx % 768, tap = idx / 768;
  const int ky = tap / 10, kx = tap % 10;
  out[idx] = (bf16_t)w[(size_t)e * 100 + (9 - ky) * 10 + (9 - kx)];
}

// ---------------- final gather ----------------
__global__ __launch_bounds__(256) void outconv_kernel(
    const float* __restrict__ g, const float* __restrict__ tb,
    float* __restrict__ out)
{
  const int idx = blockIdx.x * 256 + threadIdx.x;
  if (idx >= 16 * 40 * 40) return;
  const int x = idx % 40, y = (idx / 40) % 40, b = idx / 1600;
  float s = tb[0];
  #pragma unroll
  for (int ky = 0; ky < 10; ++ky) {
    const int ty_ = y - 4 + ky;
    if (ty_ < 0 || ty_ >= SDIM) continue;
    #pragma unroll
    for (int kx = 0; kx < 10; ++kx) {
      const int tx_ = x - 4 + kx;
      if (tx_ < 0 || tx_ >= SDIM) continue;
      s += g[((size_t)b * LLEN + ty_ * SDIM + tx_) * 100 + ky * 10 + kx];
    }
  }
  out[idx] = s;
}

// ============================================================================
extern "C" void kernel_launch(void* const* d_in, const int* in_sizes, int n_in,
                              void* d_out, int out_size, void* d_ws, size_t ws_size,
                              hipStream_t stream)
{
  const float* x       = (const float*)d_in[0];
  const float* conv_w  = (const float*)d_in[1];
  const float* conv_b  = (const float*)d_in[2];
  const float* pos     = (const float*)d_in[3];
  const float* ln1_w   = (const float*)d_in[4];
  const float* ln1_b   = (const float*)d_in[5];
  const float* qkv_w   = (const float*)d_in[6];
  const float* qkv_b   = (const float*)d_in[7];
  const float* proj_w  = (const float*)d_in[8];
  const float* proj_b  = (const float*)d_in[9];
  const float* ln2_w   = (const float*)d_in[10];
  const float* ln2_b   = (const float*)d_in[11];
  const float* fc1_w   = (const float*)d_in[12];
  const float* fc1_b   = (const float*)d_in[13];
  const float* fc2_w   = (const float*)d_in[14];
  const float* fc2_b   = (const float*)d_in[15];
  const float* lnf_w   = (const float*)d_in[16];
  const float* lnf_b   = (const float*)d_in[17];
  const float* tconv_w = (const float*)d_in[18];
  const float* tconv_b = (const float*)d_in[19];
  float* out = (float*)d_out;

  // ---- workspace tiers (bf16 t): nch=1 262MB / nch=2 180MB / nch=4 138MB
  const int nch = (ws_size >= 262200000UL) ? 1
                : (ws_size >= 179500000UL) ? 2 : 4;
  const int cht = TOKENS / nch;

  char* p = (char*)d_ws;
  auto alloc = [&](size_t bytes) {
    char* r = p;
    p += (bytes + 255) & ~(size_t)255;
    return r;
  };
  bf16_t* wbuf = (bf16_t*)alloc((size_t)768 * 9216 * 2);
  bf16_t* t    = (bf16_t*)alloc((size_t)TOKENS * EDIM * 2);
  bf16_t* ybuf = (bf16_t*)alloc((size_t)TOKENS * EDIM * 2);
  bf16_t* hbuf = (bf16_t*)alloc((size_t)cht * 3072 * 2);

  bf16_t* Wq = wbuf;
  bf16_t* Wp = Wq + (size_t)2304 * 768;
  bf16_t* W1 = Wp + (size_t)768 * 768;
  bf16_t* W2 = W1 + (size_t)3072 * 768;

  auto g4 = [&](int epi, const bf16_t* A, const bf16_t* Bt,
                const float* bias, bf16_t* bo, const float* pe,
                int M, int N, int K) {
    const int mtiles = (M + 127) / 128;
    const int ntn = N / 128;
    const int nwg = mtiles * ntn;
    switch (epi) {
      case EPI_T_POS: gemm4_kernel<EPI_T_POS><<<nwg, 256, 0, stream>>>(A, Bt, bias, nullptr, bo, pe, M, N, K, ntn, nwg, mtiles); break;
      case EPI_BF16:  gemm4_kernel<EPI_BF16 ><<<nwg, 256, 0, stream>>>(A, Bt, bias, nullptr, bo, pe, M, N, K, ntn, nwg, mtiles); break;
      case EPI_ADD_T: gemm4_kernel<EPI_ADD_T><<<nwg, 256, 0, stream>>>(A, Bt, bias, nullptr, bo, pe, M, N, K, ntn, nwg, mtiles); break;
      default:        gemm4_kernel<EPI_GELU ><<<nwg, 256, 0, stream>>>(A, Bt, bias, nullptr, bo, pe, M, N, K, ntn, nwg, mtiles); break;
    }
  };

  // ---- conv1 as chunked im2col GEMM -> t (+bias +pos_embed), bf16 ----
  convw_kernel<<<(768 * 1216) / 256, 256, 0, stream>>>(conv_w, wbuf);
  for (int c = 0; c < nch; ++c) {
    const int tok0 = c * cht;
    im2col_kernel<<<(unsigned)(((size_t)cht * 1216 + 255) / 256), 256, 0, stream>>>(x, hbuf, tok0, cht);
    g4(EPI_T_POS, hbuf, wbuf, conv_b, t + (size_t)tok0 * EDIM, pos, cht, EDIM, 1216);
  }

  // ---- transformer layers ----
  for (int i = 0; i < 12; ++i) {
    transpose4_kernel<<<6912, 256, 0, stream>>>(
        qkv_w + (size_t)i * 768 * 2304, proj_w + (size_t)i * 768 * 768,
        fc1_w + (size_t)i * 768 * 3072, fc2_w + (size_t)i * 3072 * 768,
        Wq, Wp, W1, W2);

    ln_kernel<<<TOKENS / 4, 256, 0, stream>>>(t, ln1_w + i * EDIM, ln1_b + i * EDIM, ybuf);
    for (int c = 0; c < nch; ++c) {
      const size_t ro = (size_t)c * cht;
      g4(EPI_BF16, ybuf + ro * EDIM, Wq, qkv_b + i * 2304, hbuf, nullptr, cht, 2304, 768);
      attn_kernel<<<(16 / nch) * SDIM * 12, 256, 0, stream>>>(hbuf, ybuf + ro * EDIM);
    }
    g4(EPI_ADD_T, ybuf, Wp, proj_b + i * EDIM, t, nullptr, TOKENS, EDIM, 768);

    ln_kernel<<<TOKENS / 4, 256, 0, stream>>>(t, ln2_w + i * EDIM, ln2_b + i * EDIM, ybuf);
    for (int c = 0; c < nch; ++c) {
      const size_t ro = (size_t)c * cht;
      g4(EPI_GELU, ybuf + ro * EDIM, W1, fc1_b + i * 3072, hbuf, nullptr, cht, 3072, 768);
      g4(EPI_ADD_T, hbuf, W2, fc2_b + i * EDIM, t + ro * EDIM, nullptr, cht, EDIM, 3072);
    }
  }

  // ---- final LN + tconv head ----
  ln_kernel<<<TOKENS / 4, 256, 0, stream>>>(t, lnf_w, lnf_b, ybuf);
  tconvw_kernel<<<(100 * 768) / 256, 256, 0, stream>>>(tconv_w, wbuf);
  gemm128_f32<<<dim3((TOKENS + 127) / 128, 1), 256, 0, stream>>>(ybuf, wbuf, (float*)hbuf, TOKENS, 100, 768);
  outconv_kernel<<<100, 256, 0, stream>>>((const float*)hbuf, tconv_b, out);
}